// Round 3
// baseline (807.020 us; speedup 1.0000x reference)
//
#include <hip/hip_runtime.h>

// DistMult: out[n1,n2] = (input1 * w[type]) @ input2^T + bias
// n1=n2=8192, d=512, fp32 in/out.
// SINGLE fused kernel, ZERO workspace: fp32->bf16 convert (w_r scale on A)
// reg-staged into double-buffered LDS, 256x256 bf16 MFMA NT-GEMM, BK=64.
// T14 split staging (issue loads early, convert+ds_write late), kk-split
// fragment reads to stay under the 256-VGPR cap, 2-bit XOR LDS swizzle.
// Fallback: fused 128x128 with 64 KiB STATIC LDS (no attribute needed).

#define N1 8192
#define N2 8192
#define DK 512
#define NT 8   // K-tiles of 64

typedef short bf16x8 __attribute__((ext_vector_type(8)));
typedef float f32x4  __attribute__((ext_vector_type(4)));

// Proven RTNE fp32->bf16 (bitwise-identical numerics to the passing kernels).
__device__ __forceinline__ unsigned int f2bf_u(float f) {
    unsigned int u = __float_as_uint(f);
    return (u + 0x7FFFu + ((u >> 16) & 1u)) >> 16;
}
__device__ __forceinline__ unsigned int pk2(float lo, float hi) {
    return f2bf_u(lo) | (f2bf_u(hi) << 16);
}

// ---------------------------------------------------------------------------
// Primary: 256x256 tile, BK=64, 8 waves (2M x 4N), dbuf 128 KiB dynamic LDS.
// LDS per tile: row-major [256][64] bf16 (128 B/row). Swizzle: byte offset
// XOR ((row>>2)&3)<<5 (flip bits 5,6 by row bits 2,3) on BOTH write and read
// -> 8 distinct 16B slots per wave access, ~conflict-free b128 ops.
// One barrier per K-tile (double buffer).
// ---------------------------------------------------------------------------
__global__ __launch_bounds__(512, 2) void fused_gemm_256(
        const float* __restrict__ in1, const float* __restrict__ in2,
        const float* __restrict__ weight, const int* __restrict__ type_index,
        const float* __restrict__ bias, float* __restrict__ C) {
    extern __shared__ char sm[];
    const int tid  = threadIdx.x;
    const int wave = tid >> 6;
    const int lane = tid & 63;
    const int quad = lane >> 4;
    const int r16  = lane & 15;
    const int wm   = wave >> 2;   // 0..1
    const int wn   = wave & 3;    // 0..3

    // Bijective XCD swizzle (grid=1024, 1024%8==0).
    const int bid = blockIdx.x;
    const int swz = (bid & 7) * 128 + (bid >> 3);
    const int bm = (swz >> 5) * 256;
    const int bn = (swz & 31) * 256;

    const float* wr = weight + (size_t)(*type_index) * DK;

    // Staging geometry: thread covers rows {rq,rq+64,rq+128,rq+192}, fp32
    // cols c8..c8+7. Row bits 2,3 == tid bits 5,6 for all four rows.
    const int rq = tid >> 3;
    const int c8 = (tid & 7) * 8;
    const float* gA = in1 + (size_t)(bm + rq) * DK + c8;
    const float* gB = in2 + (size_t)(bn + rq) * DK + c8;
    const int wflip = ((tid >> 5) & 3) << 5;
    const int woff  = rq * 128 + (((tid & 7) * 16) ^ wflip);

    // Fragment-read offsets: row = (wm*128|wn*64) + mi*16 + r16 -> row bits
    // 2,3 == r16 bits 2,3. XOR applied to the 0..127 column part (no carry).
    const int rflip = ((r16 >> 2) & 3) << 5;
    const int col0  = (quad * 16) ^ rflip;         // kk = 0
    const int col1  = (64 + quad * 16) ^ rflip;    // kk = 1
    const int rbaseA = (wm * 128 + r16) * 128;
    const int rbaseB = (wn * 64  + r16) * 128;

    f32x4 acc[8][4];
#pragma unroll
    for (int i = 0; i < 8; ++i)
#pragma unroll
        for (int j = 0; j < 4; ++j)
            acc[i][j] = (f32x4){0.f, 0.f, 0.f, 0.f};

    // --- prologue: stage tile 0 into buf0 (full: load, convert, write)
    {
        float4 w0 = *(const float4*)(wr + c8);
        float4 w1 = *(const float4*)(wr + c8 + 4);
        float4 ra0[4], ra1[4], rb0[4], rb1[4];
#pragma unroll
        for (int p = 0; p < 4; ++p) {
            const float* gap = gA + (size_t)(p * 64) * DK;
            const float* gbp = gB + (size_t)(p * 64) * DK;
            ra0[p] = *(const float4*)gap;  ra1[p] = *(const float4*)(gap + 4);
            rb0[p] = *(const float4*)gbp;  rb1[p] = *(const float4*)(gbp + 4);
        }
#pragma unroll
        for (int p = 0; p < 4; ++p) {
            uint4 da, db;
            da.x = pk2(ra0[p].x * w0.x, ra0[p].y * w0.y);
            da.y = pk2(ra0[p].z * w0.z, ra0[p].w * w0.w);
            da.z = pk2(ra1[p].x * w1.x, ra1[p].y * w1.y);
            da.w = pk2(ra1[p].z * w1.z, ra1[p].w * w1.w);
            *(uint4*)(sm + woff + p * 8192) = da;
            db.x = pk2(rb0[p].x, rb0[p].y);
            db.y = pk2(rb0[p].z, rb0[p].w);
            db.z = pk2(rb1[p].x, rb1[p].y);
            db.w = pk2(rb1[p].z, rb1[p].w);
            *(uint4*)(sm + 65536 + woff + p * 8192) = db;
        }
    }
    __syncthreads();

#pragma unroll 1
    for (int t = 0; t < NT; ++t) {
        const char* bufA = sm + (t & 1) * 32768;
        const char* bufB = sm + 65536 + (t & 1) * 32768;
        char* nA = sm + ((t + 1) & 1) * 32768;
        char* nB = sm + 65536 + ((t + 1) & 1) * 32768;
        const bool pf = (t + 1 < NT);

        // T14 issue-early: w first (so A-convert's waitcnt doesn't drain B),
        // then A loads, then B loads. All into regs; converts happen late.
        float4 w0, w1, ra0[4], ra1[4], rb0[4], rb1[4];
        if (pf) {
            const float* wp  = wr + (t + 1) * 64 + c8;
            w0 = *(const float4*)wp;
            w1 = *(const float4*)(wp + 4);
            const float* gap = gA + (t + 1) * 64;
#pragma unroll
            for (int p = 0; p < 4; ++p) {
                ra0[p] = *(const float4*)(gap + (size_t)(p * 64) * DK);
                ra1[p] = *(const float4*)(gap + (size_t)(p * 64) * DK + 4);
            }
            const float* gbp = gB + (t + 1) * 64;
#pragma unroll
            for (int p = 0; p < 4; ++p) {
                rb0[p] = *(const float4*)(gbp + (size_t)(p * 64) * DK);
                rb1[p] = *(const float4*)(gbp + (size_t)(p * 64) * DK + 4);
            }
        }

        // kk=0 fragments + 32 MFMA
        bf16x8 af0[8], bf0[4];
#pragma unroll
        for (int mi = 0; mi < 8; ++mi)
            af0[mi] = *(const bf16x8*)(bufA + rbaseA + mi * 2048 + col0);
#pragma unroll
        for (int ni = 0; ni < 4; ++ni)
            bf0[ni] = *(const bf16x8*)(bufB + rbaseB + ni * 2048 + col0);
        __builtin_amdgcn_s_setprio(1);
#pragma unroll
        for (int mi = 0; mi < 8; ++mi)
#pragma unroll
            for (int ni = 0; ni < 4; ++ni)
                acc[mi][ni] = __builtin_amdgcn_mfma_f32_16x16x32_bf16(
                    af0[mi], bf0[ni], acc[mi][ni], 0, 0, 0);
        __builtin_amdgcn_s_setprio(0);

        // write-late A(t+1): waits only on the A loads (B still in flight);
        // overlaps the kk=1 reads/MFMAs below; frees 32 staging regs.
        if (pf) {
#pragma unroll
            for (int p = 0; p < 4; ++p) {
                uint4 da;
                da.x = pk2(ra0[p].x * w0.x, ra0[p].y * w0.y);
                da.y = pk2(ra0[p].z * w0.z, ra0[p].w * w0.w);
                da.z = pk2(ra1[p].x * w1.x, ra1[p].y * w1.y);
                da.w = pk2(ra1[p].z * w1.z, ra1[p].w * w1.w);
                *(uint4*)(nA + woff + p * 8192) = da;
            }
        }

        // kk=1 fragments + 32 MFMA
        bf16x8 af1[8], bf1[4];
#pragma unroll
        for (int mi = 0; mi < 8; ++mi)
            af1[mi] = *(const bf16x8*)(bufA + rbaseA + mi * 2048 + col1);
#pragma unroll
        for (int ni = 0; ni < 4; ++ni)
            bf1[ni] = *(const bf16x8*)(bufB + rbaseB + ni * 2048 + col1);
        __builtin_amdgcn_s_setprio(1);
#pragma unroll
        for (int mi = 0; mi < 8; ++mi)
#pragma unroll
            for (int ni = 0; ni < 4; ++ni)
                acc[mi][ni] = __builtin_amdgcn_mfma_f32_16x16x32_bf16(
                    af1[mi], bf1[ni], acc[mi][ni], 0, 0, 0);
        __builtin_amdgcn_s_setprio(0);

        // write-late B(t+1)
        if (pf) {
#pragma unroll
            for (int p = 0; p < 4; ++p) {
                uint4 db;
                db.x = pk2(rb0[p].x, rb0[p].y);
                db.y = pk2(rb0[p].z, rb0[p].w);
                db.z = pk2(rb1[p].x, rb1[p].y);
                db.w = pk2(rb1[p].z, rb1[p].w);
                *(uint4*)(nB + woff + p * 8192) = db;
            }
        }
        __syncthreads();   // ds_writes drained (lgkmcnt) + block-wide reads done
    }

    // Epilogue: C/D mapping col=lane&15, row=quad*4+reg (verified m89/m91).
    const float bv = bias[0];
#pragma unroll
    for (int mi = 0; mi < 8; ++mi) {
        const int row0 = bm + wm * 128 + mi * 16 + quad * 4;
#pragma unroll
        for (int ni = 0; ni < 4; ++ni) {
            const int col = bn + wn * 64 + ni * 16 + r16;
#pragma unroll
            for (int r = 0; r < 4; ++r)
                C[(size_t)(row0 + r) * N2 + col] = acc[mi][ni][r] + bv;
        }
    }
}

// ---------------------------------------------------------------------------
// Fallback: fused 128x128, BK=64, 8 waves (2M x 4N), dbuf 64 KiB STATIC LDS
// (no hipFuncSetAttribute needed). 2 blocks/CU. Same swizzle/numerics.
// ---------------------------------------------------------------------------
__global__ __launch_bounds__(512, 4) void fused_gemm_128(
        const float* __restrict__ in1, const float* __restrict__ in2,
        const float* __restrict__ weight, const int* __restrict__ type_index,
        const float* __restrict__ bias, float* __restrict__ C) {
    __shared__ __align__(16) char sm[65536];   // A: 0..32K (2x16K), B: 32K..64K
    const int tid  = threadIdx.x;
    const int wave = tid >> 6;
    const int lane = tid & 63;
    const int quad = lane >> 4;
    const int r16  = lane & 15;
    const int wm   = wave >> 2;   // 0..1
    const int wn   = wave & 3;    // 0..3

    const int bid = blockIdx.x;   // grid 4096, 4096%8==0
    const int swz = (bid & 7) * 512 + (bid >> 3);
    const int bm = (swz >> 6) * 128;
    const int bn = (swz & 63) * 128;

    const float* wr = weight + (size_t)(*type_index) * DK;

    const int rq = tid >> 3;          // rows rq, rq+64
    const int c8 = (tid & 7) * 8;
    const float* gA = in1 + (size_t)(bm + rq) * DK + c8;
    const float* gB = in2 + (size_t)(bn + rq) * DK + c8;
    const int wflip = ((tid >> 5) & 3) << 5;
    const int woff  = rq * 128 + (((tid & 7) * 16) ^ wflip);

    const int rflip = ((r16 >> 2) & 3) << 5;
    const int col0  = (quad * 16) ^ rflip;
    const int col1  = (64 + quad * 16) ^ rflip;
    const int rbaseA = (wm * 64 + r16) * 128;
    const int rbaseB = (wn * 32 + r16) * 128;

    f32x4 acc[4][2];
#pragma unroll
    for (int i = 0; i < 4; ++i)
#pragma unroll
        for (int j = 0; j < 2; ++j)
            acc[i][j] = (f32x4){0.f, 0.f, 0.f, 0.f};

    {   // prologue tile 0
        float4 w0 = *(const float4*)(wr + c8);
        float4 w1 = *(const float4*)(wr + c8 + 4);
        float4 ra0[2], ra1[2], rb0[2], rb1[2];
#pragma unroll
        for (int p = 0; p < 2; ++p) {
            const float* gap = gA + (size_t)(p * 64) * DK;
            const float* gbp = gB + (size_t)(p * 64) * DK;
            ra0[p] = *(const float4*)gap;  ra1[p] = *(const float4*)(gap + 4);
            rb0[p] = *(const float4*)gbp;  rb1[p] = *(const float4*)(gbp + 4);
        }
#pragma unroll
        for (int p = 0; p < 2; ++p) {
            uint4 da, db;
            da.x = pk2(ra0[p].x * w0.x, ra0[p].y * w0.y);
            da.y = pk2(ra0[p].z * w0.z, ra0[p].w * w0.w);
            da.z = pk2(ra1[p].x * w1.x, ra1[p].y * w1.y);
            da.w = pk2(ra1[p].z * w1.z, ra1[p].w * w1.w);
            *(uint4*)(sm + woff + p * 8192) = da;
            db.x = pk2(rb0[p].x, rb0[p].y);
            db.y = pk2(rb0[p].z, rb0[p].w);
            db.z = pk2(rb1[p].x, rb1[p].y);
            db.w = pk2(rb1[p].z, rb1[p].w);
            *(uint4*)(sm + 32768 + woff + p * 8192) = db;
        }
    }
    __syncthreads();

#pragma unroll 1
    for (int t = 0; t < NT; ++t) {
        const char* bufA = sm + (t & 1) * 16384;
        const char* bufB = sm + 32768 + (t & 1) * 16384;
        char* nA = sm + ((t + 1) & 1) * 16384;
        char* nB = sm + 32768 + ((t + 1) & 1) * 16384;
        const bool pf = (t + 1 < NT);

        float4 w0, w1, ra0[2], ra1[2], rb0[2], rb1[2];
        if (pf) {
            const float* wp  = wr + (t + 1) * 64 + c8;
            w0 = *(const float4*)wp;
            w1 = *(const float4*)(wp + 4);
            const float* gap = gA + (t + 1) * 64;
            const float* gbp = gB + (t + 1) * 64;
#pragma unroll
            for (int p = 0; p < 2; ++p) {
                ra0[p] = *(const float4*)(gap + (size_t)(p * 64) * DK);
                ra1[p] = *(const float4*)(gap + (size_t)(p * 64) * DK + 4);
            }
#pragma unroll
            for (int p = 0; p < 2; ++p) {
                rb0[p] = *(const float4*)(gbp + (size_t)(p * 64) * DK);
                rb1[p] = *(const float4*)(gbp + (size_t)(p * 64) * DK + 4);
            }
        }

        bf16x8 af0[4], bf0[2];
#pragma unroll
        for (int mi = 0; mi < 4; ++mi)
            af0[mi] = *(const bf16x8*)(bufA + rbaseA + mi * 2048 + col0);
#pragma unroll
        for (int ni = 0; ni < 2; ++ni)
            bf0[ni] = *(const bf16x8*)(bufB + rbaseB + ni * 2048 + col0);
        __builtin_amdgcn_s_setprio(1);
#pragma unroll
        for (int mi = 0; mi < 4; ++mi)
#pragma unroll
            for (int ni = 0; ni < 2; ++ni)
                acc[mi][ni] = __builtin_amdgcn_mfma_f32_16x16x32_bf16(
                    af0[mi], bf0[ni], acc[mi][ni], 0, 0, 0);
        __builtin_amdgcn_s_setprio(0);

        if (pf) {
#pragma unroll
            for (int p = 0; p < 2; ++p) {
                uint4 da;
                da.x = pk2(ra0[p].x * w0.x, ra0[p].y * w0.y);
                da.y = pk2(ra0[p].z * w0.z, ra0[p].w * w0.w);
                da.z = pk2(ra1[p].x * w1.x, ra1[p].y * w1.y);
                da.w = pk2(ra1[p].z * w1.z, ra1[p].w * w1.w);
                *(uint4*)(nA + woff + p * 8192) = da;
            }
        }

        bf16x8 af1[4], bf1[2];
#pragma unroll
        for (int mi = 0; mi < 4; ++mi)
            af1[mi] = *(const bf16x8*)(bufA + rbaseA + mi * 2048 + col1);
#pragma unroll
        for (int ni = 0; ni < 2; ++ni)
            bf1[ni] = *(const bf16x8*)(bufB + rbaseB + ni * 2048 + col1);
        __builtin_amdgcn_s_setprio(1);
#pragma unroll
        for (int mi = 0; mi < 4; ++mi)
#pragma unroll
            for (int ni = 0; ni < 2; ++ni)
                acc[mi][ni] = __builtin_amdgcn_mfma_f32_16x16x32_bf16(
                    af1[mi], bf1[ni], acc[mi][ni], 0, 0, 0);
        __builtin_amdgcn_s_setprio(0);

        if (pf) {
#pragma unroll
            for (int p = 0; p < 2; ++p) {
                uint4 db;
                db.x = pk2(rb0[p].x, rb0[p].y);
                db.y = pk2(rb0[p].z, rb0[p].w);
                db.z = pk2(rb1[p].x, rb1[p].y);
                db.w = pk2(rb1[p].z, rb1[p].w);
                *(uint4*)(nB + woff + p * 8192) = db;
            }
        }
        __syncthreads();
    }

    const float bv = bias[0];
#pragma unroll
    for (int mi = 0; mi < 4; ++mi) {
        const int row0 = bm + wm * 64 + mi * 16 + quad * 4;
#pragma unroll
        for (int ni = 0; ni < 2; ++ni) {
            const int col = bn + wn * 32 + ni * 16 + r16;
#pragma unroll
            for (int r = 0; r < 4; ++r)
                C[(size_t)(row0 + r) * N2 + col] = acc[mi][ni][r] + bv;
        }
    }
}

extern "C" void kernel_launch(void* const* d_in, const int* in_sizes, int n_in,
                              void* d_out, int out_size, void* d_ws, size_t ws_size,
                              hipStream_t stream) {
    const float* in1  = (const float*)d_in[0];
    const float* in2  = (const float*)d_in[1];
    const float* wgt  = (const float*)d_in[2];
    const float* bias = (const float*)d_in[3];
    const int*   tix  = (const int*)d_in[4];
    float* out = (float*)d_out;

    (void)d_ws; (void)ws_size;  // deliberately unused: avoid ws-poison cost

    hipError_t e = hipFuncSetAttribute(
        reinterpret_cast<const void*>(fused_gemm_256),
        hipFuncAttributeMaxDynamicSharedMemorySize, 131072);
    if (e == hipSuccess) {
        fused_gemm_256<<<dim3(1024), dim3(512), 131072, stream>>>(
            in1, in2, wgt, tix, bias, out);
    } else {
        fused_gemm_128<<<dim3(4096), dim3(512), 0, stream>>>(
            in1, in2, wgt, tix, bias, out);
    }
}

// Round 4
// 375.558 us; speedup vs baseline: 2.1489x; 2.1489x over previous
//
#include <hip/hip_runtime.h>

// DistMult: out[n1,n2] = (input1 * w[type]) @ input2^T + bias
// n1=n2=8192, d=512, fp32 in/out.
// Pass 1: fp32->bf16 convert (w_r scale fused into A).  Pass 2: m97-style
// bf16 MFMA NT-GEMM (128x128, BK=32, global_load_lds 16B) with:
//   - swapped MFMA operands -> D-layout transposed -> float4 C-stores
//     (was 64 scalar stores/thread, now 16 dwordx4)
//   - bijective XCD-aware 1D grid swizzle (4096 blocks, 4096%8==0)
// The ~200us 1GiB workspace-poison fill is an unconditional harness tax
// (measured round 3: present even with d_ws unused) — not addressable here.

#define N1 8192
#define N2 8192
#define DK 512
#define BM 128
#define BN 128
#define BK 32

typedef short bf16x8 __attribute__((ext_vector_type(8)));
typedef float f32x4 __attribute__((ext_vector_type(4)));

__device__ __forceinline__ unsigned short f2bf(float f) {
    unsigned int u = __float_as_uint(f);
    u = (u + 0x7FFFu + ((u >> 16) & 1u)) >> 16;  // round-to-nearest-even
    return (unsigned short)u;
}

// One pass over both inputs: A-region gets w_r scaling, B-region straight cast.
__global__ __launch_bounds__(256) void convert_kernel(
        const float* __restrict__ in1, const float* __restrict__ in2,
        const float* __restrict__ weight, const int* __restrict__ type_index,
        unsigned short* __restrict__ a_bf, unsigned short* __restrict__ b_bf) {
    const int QA = N1 * DK / 4;
    int i = blockIdx.x * blockDim.x + threadIdx.x;
    if (i < QA) {
        float4 v = reinterpret_cast<const float4*>(in1)[i];
        int c4 = i & (DK / 4 - 1);
        float4 w = reinterpret_cast<const float4*>(weight + (size_t)(*type_index) * DK)[c4];
        ushort4 o;
        o.x = f2bf(v.x * w.x);
        o.y = f2bf(v.y * w.y);
        o.z = f2bf(v.z * w.z);
        o.w = f2bf(v.w * w.w);
        reinterpret_cast<ushort4*>(a_bf)[i] = o;
    } else {
        int j = i - QA;
        float4 v = reinterpret_cast<const float4*>(in2)[j];
        ushort4 o;
        o.x = f2bf(v.x);
        o.y = f2bf(v.y);
        o.z = f2bf(v.z);
        o.w = f2bf(v.w);
        reinterpret_cast<ushort4*>(b_bf)[j] = o;
    }
}

// NT GEMM: C[m][n] = sum_k A[m][k]*B[n][k] + bias. A,B bf16 row-major [*,DK].
// Block 256 thr = 4 waves; 128x128 C-tile; each wave a 64x64 sub-tile via
// 4x4 of mfma_f32_16x16x32_bf16. Operands SWAPPED vs the classic layout:
// D = mfma(B_frag, A_frag) so D-row <-> our N-index, D-col <-> our M-index;
// each thread then holds 4 consecutive C-columns per acc -> dwordx4 stores.
__global__ __launch_bounds__(256) void gemm_bt(
        const unsigned short* __restrict__ A, const unsigned short* __restrict__ B,
        const float* __restrict__ bias, float* __restrict__ C) {
    __shared__ __align__(16) unsigned short ldsA[BM * BK];  // 8 KB
    __shared__ __align__(16) unsigned short ldsB[BN * BK];  // 8 KB

    const int tid  = threadIdx.x;
    const int wave = tid >> 6;
    const int lane = tid & 63;
    const int quad = lane >> 4;
    const int r16  = lane & 15;
    const int wm   = wave & 1;   // wave's M half
    const int wn   = wave >> 1;  // wave's N half

    // Bijective XCD swizzle: 512 consecutive tiles per XCD (8 bm-rows x all
    // 64 bn) -> A-slice (1 MB bf16) L2-resident per XCD.
    const int bid = blockIdx.x;
    const int swz = (bid & 7) * 512 + (bid >> 3);
    const int bm = (swz >> 6) * BM;
    const int bn = (swz & 63) * BN;

    f32x4 acc[4][4];
#pragma unroll
    for (int i = 0; i < 4; ++i)
#pragma unroll
        for (int j = 0; j < 4; ++j)
            acc[i][j] = (f32x4){0.f, 0.f, 0.f, 0.f};

    // global_load_lds staging (verified): chunk c = wave*2+it covers tile rows
    // [c*16,c*16+16); lane -> row c*16 + lane/4, col (lane&3)*8; LDS dest =
    // base + lane*16B (lane-contiguous row-major).
    const int srow = wave * 32 + (lane >> 2);
    const int scol = (lane & 3) * 8;
    const unsigned short* ag0 = A + (size_t)(bm + srow) * DK + scol;
    const unsigned short* ag1 = ag0 + 16 * DK;
    const unsigned short* bg0 = B + (size_t)(bn + srow) * DK + scol;
    const unsigned short* bg1 = bg0 + 16 * DK;

    unsigned short* la0 = &ldsA[wave * 1024];
    unsigned short* la1 = &ldsA[wave * 1024 + 512];
    unsigned short* lb0 = &ldsB[wave * 1024];
    unsigned short* lb1 = &ldsB[wave * 1024 + 512];

    for (int kt = 0; kt < DK; kt += BK) {
        __builtin_amdgcn_global_load_lds(ag0 + kt, la0, 16, 0, 0);
        __builtin_amdgcn_global_load_lds(ag1 + kt, la1, 16, 0, 0);
        __builtin_amdgcn_global_load_lds(bg0 + kt, lb0, 16, 0, 0);
        __builtin_amdgcn_global_load_lds(bg1 + kt, lb1, 16, 0, 0);
        __syncthreads();

        // Fragments: row = r16-based, col = quad*8 -> ds_read_b128.
        bf16x8 af[4], bfr[4];
#pragma unroll
        for (int mi = 0; mi < 4; ++mi)
            af[mi] = *(const bf16x8*)&ldsA[(wm * 64 + mi * 16 + r16) * BK + quad * 8];
#pragma unroll
        for (int ni = 0; ni < 4; ++ni)
            bfr[ni] = *(const bf16x8*)&ldsB[(wn * 64 + ni * 16 + r16) * BK + quad * 8];

        // SWAPPED operands: B-frag as MFMA-A, A-frag as MFMA-B.
        // Products and k-accumulation order identical; D lands transposed.
#pragma unroll
        for (int mi = 0; mi < 4; ++mi)
#pragma unroll
            for (int ni = 0; ni < 4; ++ni)
                acc[mi][ni] = __builtin_amdgcn_mfma_f32_16x16x32_bf16(
                    bfr[ni], af[mi], acc[mi][ni], 0, 0, 0);
        __syncthreads();
    }

    // Epilogue with swapped D-mapping: D col (lane&15) <-> M, D row
    // (quad*4+reg) <-> N. Thread holds C[row = ..mi..+r16]
    // [col = ..ni..+quad*4 .. +3] -> one dwordx4 store per (mi,ni).
    const float bv = bias[0];
#pragma unroll
    for (int mi = 0; mi < 4; ++mi) {
        const int row = bm + wm * 64 + mi * 16 + r16;
#pragma unroll
        for (int ni = 0; ni < 4; ++ni) {
            const int col = bn + wn * 64 + ni * 16 + quad * 4;
            f32x4 v = acc[mi][ni];
            v[0] += bv; v[1] += bv; v[2] += bv; v[3] += bv;
            *reinterpret_cast<f32x4*>(&C[(size_t)row * N2 + col]) = v;
        }
    }
}

// Fallback if workspace is too small for the bf16 copies (correct but slow).
__global__ void naive_kernel(const float* __restrict__ in1, const float* __restrict__ in2,
                             const float* __restrict__ weight, const int* __restrict__ type_index,
                             const float* __restrict__ bias, float* __restrict__ out) {
    int col = blockIdx.x * 16 + threadIdx.x;
    int row = blockIdx.y * 16 + threadIdx.y;
    const float* wr = weight + (size_t)(*type_index) * DK;
    float s = 0.f;
    for (int k = 0; k < DK; ++k)
        s += in1[(size_t)row * DK + k] * wr[k] * in2[(size_t)col * DK + k];
    out[(size_t)row * N2 + col] = s + bias[0];
}

extern "C" void kernel_launch(void* const* d_in, const int* in_sizes, int n_in,
                              void* d_out, int out_size, void* d_ws, size_t ws_size,
                              hipStream_t stream) {
    const float* in1  = (const float*)d_in[0];
    const float* in2  = (const float*)d_in[1];
    const float* wgt  = (const float*)d_in[2];
    const float* bias = (const float*)d_in[3];
    const int*   tix  = (const int*)d_in[4];
    float* out = (float*)d_out;

    const size_t need = 2ull * (N1 + N2) * DK;  // bf16 copies of A(scaled)+B = 16 MB
    if (ws_size >= need) {
        unsigned short* a_bf = (unsigned short*)d_ws;
        unsigned short* b_bf = a_bf + (size_t)N1 * DK;

        const int total4 = (N1 + N2) * DK / 4;
        convert_kernel<<<total4 / 256, 256, 0, stream>>>(in1, in2, wgt, tix, a_bf, b_bf);

        gemm_bt<<<dim3((N1 / BM) * (N2 / BN)), 256, 0, stream>>>(a_bf, b_bf, bias, out);
    } else {
        dim3 grid(N2 / 16, N1 / 16);
        dim3 blk(16, 16);
        naive_kernel<<<grid, blk, 0, stream>>>(in1, in2, wgt, tix, bias, out);
    }
}

// Round 5
// 348.359 us; speedup vs baseline: 2.3166x; 1.0781x over previous
//
#include <hip/hip_runtime.h>

// DistMult: out[n1,n2] = (input1 * w[type]) @ input2^T + bias
// n1=n2=8192, d=512, fp32 in/out.
// Pass 1: fp32->bf16 convert (w_r scale fused into A).
// Pass 2: r0-verified m97-style bf16 MFMA NT-GEMM (128x128, BK=32,
//         global_load_lds 16B, 2D grid) with ONE change vs r0:
//         epilogue stages C through LDS so each wave store issues
//         128 B-contiguous segments (was 64 B) — write-coalescing fix.
// Known harness tax: ~180-200us unconditional 1 GiB ws-poison fill in the
// timed region (measured r3: present even with d_ws unused).

#define N1 8192
#define N2 8192
#define DK 512
#define BM 128
#define BN 128
#define BK 32

typedef short bf16x8 __attribute__((ext_vector_type(8)));
typedef float f32x4 __attribute__((ext_vector_type(4)));

__device__ __forceinline__ unsigned short f2bf(float f) {
    unsigned int u = __float_as_uint(f);
    u = (u + 0x7FFFu + ((u >> 16) & 1u)) >> 16;  // round-to-nearest-even
    return (unsigned short)u;
}

// One pass over both inputs: A-region gets w_r scaling, B-region straight cast.
__global__ __launch_bounds__(256) void convert_kernel(
        const float* __restrict__ in1, const float* __restrict__ in2,
        const float* __restrict__ weight, const int* __restrict__ type_index,
        unsigned short* __restrict__ a_bf, unsigned short* __restrict__ b_bf) {
    const int QA = N1 * DK / 4;
    int i = blockIdx.x * blockDim.x + threadIdx.x;
    if (i < QA) {
        float4 v = reinterpret_cast<const float4*>(in1)[i];
        int c4 = i & (DK / 4 - 1);
        float4 w = reinterpret_cast<const float4*>(weight + (size_t)(*type_index) * DK)[c4];
        ushort4 o;
        o.x = f2bf(v.x * w.x);
        o.y = f2bf(v.y * w.y);
        o.z = f2bf(v.z * w.z);
        o.w = f2bf(v.w * w.w);
        reinterpret_cast<ushort4*>(a_bf)[i] = o;
    } else {
        int j = i - QA;
        float4 v = reinterpret_cast<const float4*>(in2)[j];
        ushort4 o;
        o.x = f2bf(v.x);
        o.y = f2bf(v.y);
        o.z = f2bf(v.z);
        o.w = f2bf(v.w);
        reinterpret_cast<ushort4*>(b_bf)[j] = o;
    }
}

// NT GEMM: C[m][n] = sum_k A[m][k]*B[n][k] + bias. A,B bf16 row-major [*,DK].
// Block 256 thr = 4 waves; 128x128 C-tile; each wave a 64x64 sub-tile via
// 4x4 of mfma_f32_16x16x32_bf16. K-loop identical to the r0-verified kernel.
__global__ __launch_bounds__(256) void gemm_bt(
        const unsigned short* __restrict__ A, const unsigned short* __restrict__ B,
        const float* __restrict__ bias, float* __restrict__ C) {
    __shared__ __align__(16) unsigned short ldsA[BM * BK];  // 8 KB
    __shared__ __align__(16) unsigned short ldsB[BN * BK];  // 8 KB
    __shared__ __align__(16) float ldsC[32 * 132];          // 16.9 KB epilogue stage

    const int tid  = threadIdx.x;
    const int wave = tid >> 6;
    const int lane = tid & 63;
    const int quad = lane >> 4;
    const int r16  = lane & 15;
    const int wm   = wave & 1;   // wave's M half
    const int wn   = wave >> 1;  // wave's N half

    const int bm = blockIdx.y * BM;
    const int bn = blockIdx.x * BN;

    f32x4 acc[4][4];
#pragma unroll
    for (int i = 0; i < 4; ++i)
#pragma unroll
        for (int j = 0; j < 4; ++j)
            acc[i][j] = (f32x4){0.f, 0.f, 0.f, 0.f};

    // global_load_lds staging (verified): chunk c = wave*2+it covers tile rows
    // [c*16,c*16+16); lane -> row c*16 + lane/4, col (lane&3)*8; LDS dest =
    // base + lane*16B (lane-contiguous row-major).
    const int srow = wave * 32 + (lane >> 2);
    const int scol = (lane & 3) * 8;
    const unsigned short* ag0 = A + (size_t)(bm + srow) * DK + scol;
    const unsigned short* ag1 = ag0 + 16 * DK;
    const unsigned short* bg0 = B + (size_t)(bn + srow) * DK + scol;
    const unsigned short* bg1 = bg0 + 16 * DK;

    unsigned short* la0 = &ldsA[wave * 1024];
    unsigned short* la1 = &ldsA[wave * 1024 + 512];
    unsigned short* lb0 = &ldsB[wave * 1024];
    unsigned short* lb1 = &ldsB[wave * 1024 + 512];

    for (int kt = 0; kt < DK; kt += BK) {
        __builtin_amdgcn_global_load_lds(ag0 + kt, la0, 16, 0, 0);
        __builtin_amdgcn_global_load_lds(ag1 + kt, la1, 16, 0, 0);
        __builtin_amdgcn_global_load_lds(bg0 + kt, lb0, 16, 0, 0);
        __builtin_amdgcn_global_load_lds(bg1 + kt, lb1, 16, 0, 0);
        __syncthreads();

        bf16x8 af[4], bfr[4];
#pragma unroll
        for (int mi = 0; mi < 4; ++mi)
            af[mi] = *(const bf16x8*)&ldsA[(wm * 64 + mi * 16 + r16) * BK + quad * 8];
#pragma unroll
        for (int ni = 0; ni < 4; ++ni)
            bfr[ni] = *(const bf16x8*)&ldsB[(wn * 64 + ni * 16 + r16) * BK + quad * 8];

#pragma unroll
        for (int mi = 0; mi < 4; ++mi)
#pragma unroll
            for (int ni = 0; ni < 4; ++ni)
                acc[mi][ni] = __builtin_amdgcn_mfma_f32_16x16x32_bf16(
                    af[mi], bfr[ni], acc[mi][ni], 0, 0, 0);
        __syncthreads();
    }

    // Epilogue via LDS: acc layout (verified m89/m91): acc[mi][ni][r] =
    // C[bm + wm*64 + mi*16 + quad*4 + r][bn + wn*64 + ni*16 + r16].
    // Per mi-chunk: 32 LDS rows (wm*16 + quad*4 + r) x 128 cols, stride 132
    // (write banks 2-way = free). Read back: thread -> lds row tid>>3,
    // col ((tid&7)+(tid>>3))&7)*4 + 32i -> per wave-store 8 rows x 128 B
    // contiguous segments, dwordx4.
    const float bv = bias[0];
    const int lrow = wm * 16 + quad * 4;
    const int lcol = wn * 64 + r16;
    const int tr = tid >> 3;                       // lds row 0..31
    const int ca = (((tid & 7) + (tid >> 3)) & 7) * 4;  // rotated col group
    const int grow_off = (tr >> 4) * 64 + (tr & 15);    // wm*64 + quad*4+r part
#pragma unroll
    for (int mi = 0; mi < 4; ++mi) {
#pragma unroll
        for (int ni = 0; ni < 4; ++ni)
#pragma unroll
            for (int r = 0; r < 4; ++r)
                ldsC[(lrow + r) * 132 + lcol + ni * 16] = acc[mi][ni][r] + bv;
        __syncthreads();

        float* cp = &C[(size_t)(bm + grow_off + mi * 16) * N2 + bn];
        const float* lp = &ldsC[tr * 132];
#pragma unroll
        for (int i = 0; i < 4; ++i)
            *reinterpret_cast<f32x4*>(cp + ca + 32 * i) =
                *reinterpret_cast<const f32x4*>(lp + ca + 32 * i);
        __syncthreads();
    }
}

// Fallback if workspace is too small for the bf16 copies (correct but slow).
__global__ void naive_kernel(const float* __restrict__ in1, const float* __restrict__ in2,
                             const float* __restrict__ weight, const int* __restrict__ type_index,
                             const float* __restrict__ bias, float* __restrict__ out) {
    int col = blockIdx.x * 16 + threadIdx.x;
    int row = blockIdx.y * 16 + threadIdx.y;
    const float* wr = weight + (size_t)(*type_index) * DK;
    float s = 0.f;
    for (int k = 0; k < DK; ++k)
        s += in1[(size_t)row * DK + k] * wr[k] * in2[(size_t)col * DK + k];
    out[(size_t)row * N2 + col] = s + bias[0];
}

extern "C" void kernel_launch(void* const* d_in, const int* in_sizes, int n_in,
                              void* d_out, int out_size, void* d_ws, size_t ws_size,
                              hipStream_t stream) {
    const float* in1  = (const float*)d_in[0];
    const float* in2  = (const float*)d_in[1];
    const float* wgt  = (const float*)d_in[2];
    const float* bias = (const float*)d_in[3];
    const int*   tix  = (const int*)d_in[4];
    float* out = (float*)d_out;

    const size_t need = 2ull * (N1 + N2) * DK;  // bf16 copies of A(scaled)+B = 16 MB
    if (ws_size >= need) {
        unsigned short* a_bf = (unsigned short*)d_ws;
        unsigned short* b_bf = a_bf + (size_t)N1 * DK;

        const int total4 = (N1 + N2) * DK / 4;
        convert_kernel<<<total4 / 256, 256, 0, stream>>>(in1, in2, wgt, tix, a_bf, b_bf);

        dim3 grid(N2 / BN, N1 / BM);
        gemm_bt<<<grid, 256, 0, stream>>>(a_bf, b_bf, bias, out);
    } else {
        dim3 grid(N2 / 16, N1 / 16);
        dim3 blk(16, 16);
        naive_kernel<<<grid, blk, 0, stream>>>(in1, in2, wgt, tix, bias, out);
    }
}

// Round 6
// 340.087 us; speedup vs baseline: 2.3730x; 1.0243x over previous
//
#include <hip/hip_runtime.h>

// DistMult: out[n1,n2] = (input1 * w[type]) @ input2^T + bias
// n1=n2=8192, d=512, fp32 in/out.
// Pass 1: fp32->bf16 convert (w_r scale fused into A).
// Pass 2: m97-style bf16 MFMA NT-GEMM, 128x128 tile, now BK=64:
//   - half the barrier drains vs BK=32 (8 K-iters, 32 MFMA/barrier-pair)
//   - T2 XOR swizzle (linear LDS dest, inverse-swizzled global source slot,
//     swizzled ds_read slot) -> conflict-free ds_read_b128 at 128B row stride
//   - kk-split fragment reads keep VGPR ~= r0's 164 (3 blocks/CU)
//   - accumulation order over k identical to the verified r0 kernel
// Known harness tax: ~170-200us unconditional 1 GiB ws-poison fill in the
// timed region (measured r3: present even with d_ws unused).

#define N1 8192
#define N2 8192
#define DK 512
#define BM 128
#define BN 128
#define BK 64

typedef short bf16x8 __attribute__((ext_vector_type(8)));
typedef float f32x4 __attribute__((ext_vector_type(4)));

__device__ __forceinline__ unsigned short f2bf(float f) {
    unsigned int u = __float_as_uint(f);
    u = (u + 0x7FFFu + ((u >> 16) & 1u)) >> 16;  // round-to-nearest-even
    return (unsigned short)u;
}

// One pass over both inputs: A-region gets w_r scaling, B-region straight cast.
__global__ __launch_bounds__(256) void convert_kernel(
        const float* __restrict__ in1, const float* __restrict__ in2,
        const float* __restrict__ weight, const int* __restrict__ type_index,
        unsigned short* __restrict__ a_bf, unsigned short* __restrict__ b_bf) {
    const int QA = N1 * DK / 4;
    int i = blockIdx.x * blockDim.x + threadIdx.x;
    if (i < QA) {
        float4 v = reinterpret_cast<const float4*>(in1)[i];
        int c4 = i & (DK / 4 - 1);
        float4 w = reinterpret_cast<const float4*>(weight + (size_t)(*type_index) * DK)[c4];
        ushort4 o;
        o.x = f2bf(v.x * w.x);
        o.y = f2bf(v.y * w.y);
        o.z = f2bf(v.z * w.z);
        o.w = f2bf(v.w * w.w);
        reinterpret_cast<ushort4*>(a_bf)[i] = o;
    } else {
        int j = i - QA;
        float4 v = reinterpret_cast<const float4*>(in2)[j];
        ushort4 o;
        o.x = f2bf(v.x);
        o.y = f2bf(v.y);
        o.z = f2bf(v.z);
        o.w = f2bf(v.w);
        reinterpret_cast<ushort4*>(b_bf)[j] = o;
    }
}

// NT GEMM: C[m][n] = sum_k A[m][k]*B[n][k] + bias. A,B bf16 row-major [*,DK].
// Block 256 thr = 4 waves; 128x128 C-tile; each wave a 64x64 sub-tile via
// 4x4 of mfma_f32_16x16x32_bf16, BK=64 (kk = 0,1 within each staged tile).
//
// LDS tile per matrix: [128 rows][64 cols] bf16 = 16 KB, 128 B/row.
// Staging: wave w stages chunks w*4+i (i=0..3); chunk = 8 rows; lane ->
//   row = (w*4+i)*8 + lane/8, LINEAR LDS slot lane&7 (dest = base+lane*16),
//   GLOBAL source col-slot = (lane&7) ^ (lane>>3)   [inverse swizzle].
// Read: logical col-slot kk*4+quad of row r lives at LDS slot
//   (kk*4+quad) ^ (r&7)  -> 8 distinct 16B slots per 8 rows: conflict-free.
__global__ __launch_bounds__(256) void gemm_bt(
        const unsigned short* __restrict__ A, const unsigned short* __restrict__ B,
        const float* __restrict__ bias, float* __restrict__ C) {
    __shared__ __align__(16) unsigned short ldsA[BM * BK];  // 16 KB
    __shared__ __align__(16) unsigned short ldsB[BN * BK];  // 16 KB

    const int tid  = threadIdx.x;
    const int wave = tid >> 6;
    const int lane = tid & 63;
    const int quad = lane >> 4;
    const int r16  = lane & 15;
    const int wm   = wave & 1;   // wave's M half
    const int wn   = wave >> 1;  // wave's N half

    const int bm = blockIdx.y * BM;
    const int bn = blockIdx.x * BN;

    f32x4 acc[4][4];
#pragma unroll
    for (int i = 0; i < 4; ++i)
#pragma unroll
        for (int j = 0; j < 4; ++j)
            acc[i][j] = (f32x4){0.f, 0.f, 0.f, 0.f};

    // Staging geometry (see header comment).
    const int l8   = lane >> 3;                 // row within chunk, 0..7
    const int perm = (lane & 7) ^ l8;           // swizzled source col-slot
    const int srow = wave * 32 + l8;
    const int scol = perm * 8;                  // elements
    const unsigned short* ag = A + (size_t)(bm + srow) * DK + scol;
    const unsigned short* bg = B + (size_t)(bn + srow) * DK + scol;
    unsigned short* la = &ldsA[wave * 2048];    // 4 chunks x 512 elem
    unsigned short* lb = &ldsB[wave * 2048];

    // Swizzled read col offsets (elements) for kk=0 / kk=1.
    const int rs   = r16 & 7;
    const int col0 = ((0 * 4 + quad) ^ rs) * 8;
    const int col1 = ((1 * 4 + quad) ^ rs) * 8;

    for (int kt = 0; kt < DK; kt += BK) {
#pragma unroll
        for (int i = 0; i < 4; ++i) {
            __builtin_amdgcn_global_load_lds(ag + kt + i * 8 * DK, la + i * 512, 16, 0, 0);
            __builtin_amdgcn_global_load_lds(bg + kt + i * 8 * DK, lb + i * 512, 16, 0, 0);
        }
        __syncthreads();

        // kk = 0 : k = kt .. kt+31
        {
            bf16x8 af[4], bfr[4];
#pragma unroll
            for (int mi = 0; mi < 4; ++mi)
                af[mi] = *(const bf16x8*)&ldsA[(wm * 64 + mi * 16 + r16) * BK + col0];
#pragma unroll
            for (int ni = 0; ni < 4; ++ni)
                bfr[ni] = *(const bf16x8*)&ldsB[(wn * 64 + ni * 16 + r16) * BK + col0];
#pragma unroll
            for (int mi = 0; mi < 4; ++mi)
#pragma unroll
                for (int ni = 0; ni < 4; ++ni)
                    acc[mi][ni] = __builtin_amdgcn_mfma_f32_16x16x32_bf16(
                        af[mi], bfr[ni], acc[mi][ni], 0, 0, 0);
        }
        // kk = 1 : k = kt+32 .. kt+63
        {
            bf16x8 af[4], bfr[4];
#pragma unroll
            for (int mi = 0; mi < 4; ++mi)
                af[mi] = *(const bf16x8*)&ldsA[(wm * 64 + mi * 16 + r16) * BK + col1];
#pragma unroll
            for (int ni = 0; ni < 4; ++ni)
                bfr[ni] = *(const bf16x8*)&ldsB[(wn * 64 + ni * 16 + r16) * BK + col1];
#pragma unroll
            for (int mi = 0; mi < 4; ++mi)
#pragma unroll
                for (int ni = 0; ni < 4; ++ni)
                    acc[mi][ni] = __builtin_amdgcn_mfma_f32_16x16x32_bf16(
                        af[mi], bfr[ni], acc[mi][ni], 0, 0, 0);
        }
        __syncthreads();
    }

    // Epilogue: C/D mapping col=lane&15, row=quad*4+reg (verified m89/m91).
    const float bv = bias[0];
#pragma unroll
    for (int mi = 0; mi < 4; ++mi) {
        const int row0 = bm + wm * 64 + mi * 16 + quad * 4;
#pragma unroll
        for (int ni = 0; ni < 4; ++ni) {
            const int col = bn + wn * 64 + ni * 16 + r16;
#pragma unroll
            for (int r = 0; r < 4; ++r)
                C[(size_t)(row0 + r) * N2 + col] = acc[mi][ni][r] + bv;
        }
    }
}

// Fallback if workspace is too small for the bf16 copies (correct but slow).
__global__ void naive_kernel(const float* __restrict__ in1, const float* __restrict__ in2,
                             const float* __restrict__ weight, const int* __restrict__ type_index,
                             const float* __restrict__ bias, float* __restrict__ out) {
    int col = blockIdx.x * 16 + threadIdx.x;
    int row = blockIdx.y * 16 + threadIdx.y;
    const float* wr = weight + (size_t)(*type_index) * DK;
    float s = 0.f;
    for (int k = 0; k < DK; ++k)
        s += in1[(size_t)row * DK + k] * wr[k] * in2[(size_t)col * DK + k];
    out[(size_t)row * N2 + col] = s + bias[0];
}

extern "C" void kernel_launch(void* const* d_in, const int* in_sizes, int n_in,
                              void* d_out, int out_size, void* d_ws, size_t ws_size,
                              hipStream_t stream) {
    const float* in1  = (const float*)d_in[0];
    const float* in2  = (const float*)d_in[1];
    const float* wgt  = (const float*)d_in[2];
    const float* bias = (const float*)d_in[3];
    const int*   tix  = (const int*)d_in[4];
    float* out = (float*)d_out;

    const size_t need = 2ull * (N1 + N2) * DK;  // bf16 copies of A(scaled)+B = 16 MB
    if (ws_size >= need) {
        unsigned short* a_bf = (unsigned short*)d_ws;
        unsigned short* b_bf = a_bf + (size_t)N1 * DK;

        const int total4 = (N1 + N2) * DK / 4;
        convert_kernel<<<total4 / 256, 256, 0, stream>>>(in1, in2, wgt, tix, a_bf, b_bf);

        dim3 grid(N2 / BN, N1 / BM);
        gemm_bt<<<grid, 256, 0, stream>>>(a_bf, b_bf, bias, out);
    } else {
        dim3 grid(N2 / 16, N1 / 16);
        dim3 blk(16, 16);
        naive_kernel<<<grid, blk, 0, stream>>>(in1, in2, wgt, tix, bias, out);
    }
}